// Round 2
// baseline (4675.048 us; speedup 1.0000x reference)
//
#include <hip/hip_runtime.h>
#include <stdint.h>

// Problem constants (B=256, D=1024, T=128)
#define B_ROWS 256
#define DDIM   1024
#define TSTEPS 128
#define THREE_D 3072

typedef short bf16x8 __attribute__((ext_vector_type(8)));
typedef float f32x4  __attribute__((ext_vector_type(4)));
typedef unsigned short u16x8 __attribute__((ext_vector_type(8)));

static __device__ __forceinline__ unsigned short f2bf(float f) {
    union { float f; uint32_t u; } v; v.f = f;
    uint32_t u = v.u;
    uint32_t r = u + 0x7FFFu + ((u >> 16) & 1u);   // round-to-nearest-even
    return (unsigned short)(r >> 16);
}
static __device__ __forceinline__ float bf2f(unsigned short h) {
    union { uint32_t u; float f; } v; v.u = ((uint32_t)h) << 16; return v.f;
}

// ---------------------------------------------------------------------------
// Pack folded weights (steps>=1) into hi+lo bf16 pairs in MFMA B-fragment
// order. M = [Wz+Uz | Wr+Ur | Wh | Uh]  (f32 fold, then split).
// Layout: pack[ntile(0..255)][ktile(0..31)][lane(0..63)][j(0..7)]
//   col = ntile*16 + (lane&15),  k = ktile*32 + (lane>>4)*8 + j
// ---------------------------------------------------------------------------
__global__ __launch_bounds__(256) void pack_kernel(
    const float* __restrict__ W, const float* __restrict__ U,
    unsigned short* __restrict__ phi, unsigned short* __restrict__ plo)
{
    int t = blockIdx.x * 256 + threadIdx.x;   // 524288 threads
    int lane  = t & 63;
    int ktile = (t >> 6) & 31;
    int ntile = t >> 11;                       // 0..255
    int col = ntile * 16 + (lane & 15);
    int q = col >> 10;                         // wave-uniform
    int d = col & 1023;
    int k8 = ktile * 32 + ((lane >> 4) << 3);

    u16x8 ohi, olo;
    #pragma unroll
    for (int j = 0; j < 8; ++j) {
        int k = k8 + j;
        const float* wr = W + (size_t)k * THREE_D;
        const float* ur = U + (size_t)k * THREE_D;
        float v;
        if (q == 0)      v = wr[d] + ur[d];
        else if (q == 1) v = wr[1024 + d] + ur[1024 + d];
        else if (q == 2) v = wr[2048 + d];
        else             v = ur[2048 + d];
        unsigned short hi = f2bf(v);
        ohi[j] = hi;
        olo[j] = f2bf(v - bf2f(hi));
    }
    size_t base = ((size_t)(ntile * 32 + ktile) * 64 + lane) * 8;
    *(u16x8*)(phi + base) = ohi;
    *(u16x8*)(plo + base) = olo;
}

// ---------------------------------------------------------------------------
// Step 0 in exact f32 (inp = 0, h = x): gh = x @ U; gx = bias only.
// Grid 256 blocks: rt = blk>>4 (16 rows each), dt = blk&15 (64 dims each).
// 256 threads: c = tid&63 (dim within tile), rg = tid>>6 -> 4 rows each.
// ---------------------------------------------------------------------------
__global__ __launch_bounds__(256) void gru_step0(
    const float* __restrict__ x, const float* __restrict__ U,
    const float* __restrict__ bias,
    float* __restrict__ out,
    unsigned short* __restrict__ hbh, unsigned short* __restrict__ hbl)
{
    __shared__ float xt[16][64];
    const int tid = threadIdx.x;
    const int c   = tid & 63;
    const int rg  = tid >> 6;            // wave id -> 4 rows
    const int dt  = blockIdx.x & 15;
    const int rt  = blockIdx.x >> 4;

    float acc[4][3];
    #pragma unroll
    for (int rr = 0; rr < 4; ++rr) { acc[rr][0] = 0.f; acc[rr][1] = 0.f; acc[rr][2] = 0.f; }

    for (int kc = 0; kc < 16; ++kc) {
        #pragma unroll
        for (int i = 0; i < 4; ++i) {
            int e = i * 256 + tid;
            int row = e >> 6, kk = e & 63;
            xt[row][kk] = x[(size_t)(rt * 16 + row) * DDIM + kc * 64 + kk];
        }
        __syncthreads();
        #pragma unroll 4
        for (int kk = 0; kk < 64; ++kk) {
            int k = kc * 64 + kk;
            const float* up = U + (size_t)k * THREE_D + dt * 64 + c;
            float uz = up[0], ur = up[1024], uh = up[2048];
            #pragma unroll
            for (int rr = 0; rr < 4; ++rr) {
                float xv = xt[rg * 4 + rr][kk];     // wave-uniform broadcast
                acc[rr][0] += xv * uz;
                acc[rr][1] += xv * ur;
                acc[rr][2] += xv * uh;
            }
        }
        __syncthreads();
    }

    int d = dt * 64 + c;
    #pragma unroll
    for (int rr = 0; rr < 4; ++rr) {
        int row = rt * 16 + rg * 4 + rr;
        float z  = 1.0f / (1.0f + __expf(-(acc[rr][0] + bias[d])));
        float r  = 1.0f / (1.0f + __expf(-(acc[rr][1] + bias[1024 + d])));
        float hh = tanhf(bias[2048 + d] + r * acc[rr][2]);
        float hp = x[(size_t)row * DDIM + d];
        float hn = z * hp + (1.0f - z) * hh;
        out[(size_t)row * (TSTEPS * DDIM) + d] = hn;           // t = 0
        unsigned short hi = f2bf(hn);
        size_t off = (size_t)row * DDIM + d;
        hbh[off] = hi;
        hbl[off] = f2bf(hn - bf2f(hi));
    }
}

// ---------------------------------------------------------------------------
// Steps 1..127, fused GEMM (split-bf16, 3 cross terms) + gates.
// Grid 256 blocks: dt = blk&63 (16 dims), rt = blk>>6 (64 rows).
// Block = 4 waves; wave q = gate quarter q.  f32 h read from out[t-1].
// ---------------------------------------------------------------------------
__global__ __launch_bounds__(256) void gru_step(
    const unsigned short* __restrict__ phi,
    const unsigned short* __restrict__ plo,
    const unsigned short* __restrict__ hbh_in,
    const unsigned short* __restrict__ hbl_in,
    const float* __restrict__ bias,
    float* __restrict__ out,
    unsigned short* __restrict__ hbh_out,
    unsigned short* __restrict__ hbl_out,
    int t)
{
    __shared__ float gbuf[4][64][16];
    const int tid  = threadIdx.x;
    const int lane = tid & 63;
    const int q    = tid >> 6;          // wave id == gate quarter
    const int dt   = blockIdx.x & 63;   // dim tile (16 dims)
    const int rt   = blockIdx.x >> 6;   // row tile (64 rows)
    const int llow = lane & 15;
    const int lhi  = lane >> 4;

    f32x4 acc[4] = {f32x4{0,0,0,0}, f32x4{0,0,0,0}, f32x4{0,0,0,0}, f32x4{0,0,0,0}};

    const int ntile = q * 64 + dt;
    const unsigned short* bhp = phi + ((size_t)ntile * 2048 + lane) * 8;   // 32kt*64ln
    const unsigned short* blp = plo + ((size_t)ntile * 2048 + lane) * 8;
    const unsigned short* ahp = hbh_in + (size_t)(rt * 64 + llow) * DDIM + lhi * 8;
    const unsigned short* alp = hbl_in + (size_t)(rt * 64 + llow) * DDIM + lhi * 8;

    #pragma unroll 2
    for (int kt = 0; kt < 32; ++kt) {
        bf16x8 bh = *(const bf16x8*)(bhp + (size_t)kt * 512);
        bf16x8 bl = *(const bf16x8*)(blp + (size_t)kt * 512);
        const int koff = kt * 32;
        #pragma unroll
        for (int m = 0; m < 4; ++m) {
            bf16x8 ah = *(const bf16x8*)(ahp + (size_t)m * 16 * DDIM + koff);
            bf16x8 al = *(const bf16x8*)(alp + (size_t)m * 16 * DDIM + koff);
            acc[m] = __builtin_amdgcn_mfma_f32_16x16x32_bf16(ah, bh, acc[m], 0, 0, 0);
            acc[m] = __builtin_amdgcn_mfma_f32_16x16x32_bf16(al, bh, acc[m], 0, 0, 0);
            acc[m] = __builtin_amdgcn_mfma_f32_16x16x32_bf16(ah, bl, acc[m], 0, 0, 0);
        }
    }

    // C/D layout: col = lane&15, row = (lane>>4)*4 + reg  [measured m89]
    #pragma unroll
    for (int m = 0; m < 4; ++m) {
        #pragma unroll
        for (int r = 0; r < 4; ++r) {
            gbuf[q][m * 16 + lhi * 4 + r][llow] = acc[m][r];
        }
    }
    __syncthreads();

    // Gate epilogue: 64x16 = 1024 elements over 256 threads
    #pragma unroll
    for (int i = 0; i < 4; ++i) {
        int e = tid + i * 256;
        int row = e >> 4, col = e & 15;
        int d = dt * 16 + col;
        int grow = rt * 64 + row;
        float gz = gbuf[0][row][col] + bias[d];
        float gr = gbuf[1][row][col] + bias[1024 + d];
        float gx = gbuf[2][row][col] + bias[2048 + d];
        float gu = gbuf[3][row][col];
        float z  = 1.0f / (1.0f + __expf(-gz));
        float r  = 1.0f / (1.0f + __expf(-gr));
        float hh = tanhf(gx + r * gu);
        size_t orow = (size_t)grow * (TSTEPS * DDIM);
        float hp = out[orow + (size_t)(t - 1) * DDIM + d];     // f32 prev state
        float hn = z * hp + (1.0f - z) * hh;
        out[orow + (size_t)t * DDIM + d] = hn;
        unsigned short hi = f2bf(hn);
        size_t hoff = (size_t)grow * DDIM + d;
        hbh_out[hoff] = hi;
        hbl_out[hoff] = f2bf(hn - bf2f(hi));
    }
}

extern "C" void kernel_launch(void* const* d_in, const int* in_sizes, int n_in,
                              void* d_out, int out_size, void* d_ws, size_t ws_size,
                              hipStream_t stream) {
    const float* x = (const float*)d_in[0];
    const float* W = (const float*)d_in[1];
    const float* U = (const float*)d_in[2];
    const float* b = (const float*)d_in[3];
    float* out = (float*)d_out;

    char* ws = (char*)d_ws;
    // ws layout (total 18 MB; 19 MB proven available in round 1):
    unsigned short* phi = (unsigned short*)ws;                      // 8 MB
    unsigned short* plo = (unsigned short*)(ws + (8u << 20));       // 8 MB
    char* hbase = ws + (16u << 20);
    unsigned short* hbh[2] = { (unsigned short*)hbase,
                               (unsigned short*)(hbase + (512u << 10)) };   // 2x 0.5 MB
    unsigned short* hbl[2] = { (unsigned short*)(hbase + (1024u << 10)),
                               (unsigned short*)(hbase + (1536u << 10)) };  // 2x 0.5 MB

    hipLaunchKernelGGL(pack_kernel, dim3(2048), dim3(256), 0, stream, W, U, phi, plo);
    // step 0 (exact f32) writes out[:,0,:] and state buffers [0]
    hipLaunchKernelGGL(gru_step0, dim3(256), dim3(256), 0, stream, x, U, b,
                       out, hbh[0], hbl[0]);

    for (int t = 1; t < TSTEPS; ++t) {
        int src = (t - 1) & 1;
        int dst = t & 1;
        hipLaunchKernelGGL(gru_step, dim3(256), dim3(256), 0, stream,
                           phi, plo, hbh[src], hbl[src], b,
                           out, hbh[dst], hbl[dst], t);
    }
}